// Round 4
// baseline (99.428 us; speedup 1.0000x reference)
//
#include <hip/hip_runtime.h>

// Problem constants (from reference): B=4, N=256, FE=8, CIN=16, COUT=16, H=64
#define B_    4
#define N_    256
#define FE_   8
#define CIN_  16
#define COUT_ 16
#define H_    64
#define S_    32   // i-slices: each K1 block handles N_/S_ = 8 rows of i

// Math:
// out[b,j,d] = sum_c node[b,j,c] * ( Wsum[b,j,c,d] + root[c,d] )
// Wsum[b,j]  = Hsum[b,j,:] @ W2 + N*b2
// Hsum[b,j,h]= sum_i relu( edge[b,i,j,:] @ W1 + b1 )[h]
//
// ws layout: [0,4096)   W1t[64][16]  (cols of W1 + b1, one 64B K$ line per h)
//            [4096, +8MB) partial[b][j][s][h]  (K2 reads 8KB contiguous per j)

// ---- K0: pack W1^T + b1 into cache-line-per-h form (runs once, 1 block) ----
__global__ __launch_bounds__(256) void k0_pack_w1(
    const float* __restrict__ W1,   // [FE,H]
    const float* __restrict__ b1,   // [H]
    float* __restrict__ W1t)        // [64][16]: [0..7]=W1[:,h], [8]=b1[h]
{
    const int t = threadIdx.x;
    for (int idx = t; idx < H_ * 16; idx += 256) {
        const int h = idx >> 4, f = idx & 15;
        float v = 0.f;
        if (f < FE_)       v = W1[f * H_ + h];
        else if (f == FE_) v = b1[h];
        W1t[idx] = v;
    }
}

// ---- K1: partial Hsum; lane = jj (coalesced e loads); W1 via 1 s_load line/h
__global__ __launch_bounds__(256) void k1_partial_hsum(
    const float* __restrict__ edge_adj,   // [B,N,N,FE]
    const float* __restrict__ W1t,        // [64][16]
    float* __restrict__ partial)          // [B][N][S_][64]
{
    const int blk = blockIdx.x;           // s*16 + b*4 + jt
    const int s   = blk >> 4;
    const int b   = (blk >> 2) & 3;
    const int jt  = blk & 3;
    const int t    = threadIdx.x;
    const int lane = t & 63;              // jj
    const int w    = t >> 6;              // wave 0..3

    __shared__ float bufA[64][H_ + 1];    // [jj][h]
    __shared__ float bufB[64][H_ + 1];

    // this wave's 2 e-rows, fully coalesced (2 KB/row/wave)
    const int i0 = s * 8 + w * 2;
    const int j  = jt * 64 + lane;
    const float* e0p = edge_adj + (((size_t)b * N_ + i0)     * N_ + j) * FE_;
    const float* e1p = edge_adj + (((size_t)b * N_ + i0 + 1) * N_ + j) * FE_;
    const float4 e0a = ((const float4*)e0p)[0];
    const float4 e0b = ((const float4*)e0p)[1];
    const float4 e1a = ((const float4*)e1p)[0];
    const float4 e1b = ((const float4*)e1p)[1];

    float acc[H_];
    #pragma unroll
    for (int h = 0; h < H_; ++h) {
        // one 64B-aligned K$ line per h: 8 weights + bias (uniform -> s_load)
        const float* wrow = W1t + h * 16;
        const float w0 = wrow[0], w1 = wrow[1], w2 = wrow[2], w3 = wrow[3];
        const float w4 = wrow[4], w5 = wrow[5], w6 = wrow[6], w7 = wrow[7];
        const float bb = wrow[8];

        float v0 = bb, v1 = bb;
        v0 = fmaf(e0a.x, w0, v0);  v1 = fmaf(e1a.x, w0, v1);
        v0 = fmaf(e0a.y, w1, v0);  v1 = fmaf(e1a.y, w1, v1);
        v0 = fmaf(e0a.z, w2, v0);  v1 = fmaf(e1a.z, w2, v1);
        v0 = fmaf(e0a.w, w3, v0);  v1 = fmaf(e1a.w, w3, v1);
        v0 = fmaf(e0b.x, w4, v0);  v1 = fmaf(e1b.x, w4, v1);
        v0 = fmaf(e0b.y, w5, v0);  v1 = fmaf(e1b.y, w5, v1);
        v0 = fmaf(e0b.z, w6, v0);  v1 = fmaf(e1b.z, w6, v1);
        v0 = fmaf(e0b.w, w7, v0);  v1 = fmaf(e1b.w, w7, v1);

        acc[h] = fmaxf(v0, 0.f) + fmaxf(v1, 0.f);
    }

    // cross-wave reduce, no atomics (R2 lesson: LDS float atomicAdd = CAS loop)
    float (*mybuf)[H_ + 1] = (w < 2) ? bufA : bufB;
    if ((w & 1) == 0) {
        #pragma unroll
        for (int h = 0; h < H_; ++h) mybuf[lane][h] = acc[h];
    }
    __syncthreads();
    if ((w & 1) == 1) {
        #pragma unroll
        for (int h = 0; h < H_; ++h) mybuf[lane][h] += acc[h];
    }
    __syncthreads();

    // store: partial[b][j][s][h]; each iter = 256B coalesced (lane = h)
    #pragma unroll
    for (int k = 0; k < 16; ++k) {
        const int jj = w * 16 + k;
        const float v = bufA[jj][lane] + bufB[jj][lane];
        partial[(((size_t)b * N_ + jt * 64 + jj) * S_ + s) * 64 + lane] = v;
    }
}

// ---- K2: 4 j's per block; reduce partials + steps 2-3 ----
__global__ __launch_bounds__(256) void k2_output(
    const float* __restrict__ node_attr,  // [B,N,CIN]
    const float* __restrict__ W2,         // [H, CIN*COUT]
    const float* __restrict__ b2,         // [CIN*COUT]
    const float* __restrict__ root,       // [CIN,COUT]
    const float* __restrict__ partial,    // [B][N][S_][64]
    float* __restrict__ out)              // [B,N,COUT]
{
    const int blk = blockIdx.x;           // b*64 + j-group
    const int b   = blk >> 6;
    const int jg  = (blk & 63) * 4;
    const int t    = threadIdx.x;
    const int jl   = t >> 6;              // which of the 4 j's
    const int lane = t & 63;

    __shared__ float sred[4][4][64];      // [jl][sg][h]
    __shared__ float Hs4[4][H_];          // [jl][h]
    __shared__ float con[4][CIN_][COUT_];

    // phase A: reduce 32 s-slices -> Hs4. 8 KB contiguous per j, float4 loads.
    {
        const int sg = lane >> 4;         // 0..3
        const int h0 = (lane & 15) << 2;  // 0,4,..,60
        const float* base = partial + ((size_t)(b * N_ + jg + jl) * S_) * 64;
        float4 a4 = make_float4(0.f, 0.f, 0.f, 0.f);
        #pragma unroll
        for (int k = 0; k < 8; ++k) {
            const float4 v = *(const float4*)(base + (sg * 8 + k) * 64 + h0);
            a4.x += v.x; a4.y += v.y; a4.z += v.z; a4.w += v.w;
        }
        *(float4*)(&sred[jl][sg][h0]) = a4;
    }
    __syncthreads();
    Hs4[jl][lane] = sred[jl][0][lane] + sred[jl][1][lane]
                  + sred[jl][2][lane] + sred[jl][3][lane];
    __syncthreads();

    // phase B: ws_j[t] = N*b2[t] + sum_h Hs4[j][h]*W2[h][t]; 4 indep chains
    float ws0 = (float)N_ * b2[t];
    float ws1 = ws0, ws2 = ws0, ws3 = ws0;
    #pragma unroll
    for (int hq = 0; hq < 16; ++hq) {
        const int hh = hq * 4;
        const float4 hv0 = *(const float4*)(&Hs4[0][hh]);  // uniform -> broadcast
        const float4 hv1 = *(const float4*)(&Hs4[1][hh]);
        const float4 hv2 = *(const float4*)(&Hs4[2][hh]);
        const float4 hv3 = *(const float4*)(&Hs4[3][hh]);
        const float wv0 = W2[(hh + 0) * 256 + t];
        const float wv1 = W2[(hh + 1) * 256 + t];
        const float wv2 = W2[(hh + 2) * 256 + t];
        const float wv3 = W2[(hh + 3) * 256 + t];
        ws0 = fmaf(hv0.x, wv0, ws0); ws0 = fmaf(hv0.y, wv1, ws0);
        ws0 = fmaf(hv0.z, wv2, ws0); ws0 = fmaf(hv0.w, wv3, ws0);
        ws1 = fmaf(hv1.x, wv0, ws1); ws1 = fmaf(hv1.y, wv1, ws1);
        ws1 = fmaf(hv1.z, wv2, ws1); ws1 = fmaf(hv1.w, wv3, ws1);
        ws2 = fmaf(hv2.x, wv0, ws2); ws2 = fmaf(hv2.y, wv1, ws2);
        ws2 = fmaf(hv2.z, wv2, ws2); ws2 = fmaf(hv2.w, wv3, ws2);
        ws3 = fmaf(hv3.x, wv0, ws3); ws3 = fmaf(hv3.y, wv1, ws3);
        ws3 = fmaf(hv3.z, wv2, ws3); ws3 = fmaf(hv3.w, wv3, ws3);
    }

    // phase C: out[j,d] = sum_c node[j,c]*(ws_j[c,d] + root[c,d])
    {
        const int c = t >> 4, d = t & 15;
        const float rt = root[t];
        con[0][c][d] = node_attr[((size_t)(b * N_ + jg + 0)) * CIN_ + c] * (ws0 + rt);
        con[1][c][d] = node_attr[((size_t)(b * N_ + jg + 1)) * CIN_ + c] * (ws1 + rt);
        con[2][c][d] = node_attr[((size_t)(b * N_ + jg + 2)) * CIN_ + c] * (ws2 + rt);
        con[3][c][d] = node_attr[((size_t)(b * N_ + jg + 3)) * CIN_ + c] * (ws3 + rt);
    }
    __syncthreads();
    if (t < 64) {
        const int jl2 = t >> 4, d = t & 15;
        float o = 0.f;
        #pragma unroll
        for (int cc = 0; cc < CIN_; ++cc) o += con[jl2][cc][d];
        out[((size_t)(b * N_ + jg + jl2)) * COUT_ + d] = o;
    }
}

extern "C" void kernel_launch(void* const* d_in, const int* in_sizes, int n_in,
                              void* d_out, int out_size, void* d_ws, size_t ws_size,
                              hipStream_t stream) {
    const float* node_attr = (const float*)d_in[0];  // [B,N,CIN]
    const float* edge_adj  = (const float*)d_in[1];  // [B,N,N,FE]
    const float* W1        = (const float*)d_in[2];  // [FE,H]
    const float* b1        = (const float*)d_in[3];  // [H]
    const float* W2        = (const float*)d_in[4];  // [H,CIN*COUT]
    const float* b2        = (const float*)d_in[5];  // [CIN*COUT]
    const float* root      = (const float*)d_in[6];  // [CIN,COUT]
    float* out = (float*)d_out;                      // [B,N,COUT]

    float* W1t     = (float*)d_ws;                   // 4 KB
    float* partial = (float*)((char*)d_ws + 4096);   // 8 MB

    k0_pack_w1<<<dim3(1), dim3(256), 0, stream>>>(W1, b1, W1t);
    k1_partial_hsum<<<dim3(S_ * B_ * 4), dim3(256), 0, stream>>>(
        edge_adj, W1t, partial);
    k2_output<<<dim3(B_ * N_ / 4), dim3(256), 0, stream>>>(
        node_attr, W2, b2, root, partial, out);
}

// Round 5
// 79.705 us; speedup vs baseline: 1.2475x; 1.2475x over previous
//
#include <hip/hip_runtime.h>

// Problem constants (from reference): B=4, N=256, FE=8, CIN=16, COUT=16, H=64
#define B_    4
#define N_    256
#define FE_   8
#define CIN_  16
#define COUT_ 16
#define H_    64

// Single fused kernel, one block per (b,j). Lesson R1..R4: harness resets
// (256MiB ws poison fill ~42us + 7 d_in restores) are in every timing window
// (~60-65us floor) and each extra kernel dispatch costs ~5-15us -> minimize
// dispatch count, then minimize kernel time.
//
// out[b,j,d] = sum_c node[b,j,c] * ( Wsum[b,j,c,d] + root[c,d] )
// Wsum[b,j]  = Hsum[b,j,:] @ W2 + N*b2
// Hsum[b,j,h]= sum_i relu( edge[b,i,j,:] @ W1 + b1 )[h]

__global__ __launch_bounds__(256) void nnconv_fused(
    const float* __restrict__ node_attr,  // [B,N,CIN]
    const float* __restrict__ edge_adj,   // [B,N,N,FE]
    const float* __restrict__ W1,         // [FE,H]
    const float* __restrict__ b1,         // [H]
    const float* __restrict__ W2,         // [H, CIN*COUT]
    const float* __restrict__ b2,         // [CIN*COUT]
    const float* __restrict__ root,       // [CIN,COUT]
    float* __restrict__ out)              // [B,N,COUT]
{
    // XCD swizzle: MI355X assigns block n -> XCD (n % 8) round-robin.
    // Map same-XCD-consecutive blocks to consecutive j so the 4 edge rows
    // sharing one 128B cacheline (j, j+1, j+2, j+3) are fetched by ONE XCD:
    // HBM gather traffic ~33MB -> ~8.4MB, rest served from that XCD's L2.
    // (Heuristic only: wrong mapping costs bandwidth, never correctness.)
    const int Bid = blockIdx.x;
    const int p   = (Bid & 7) * 128 + (Bid >> 3);   // 0..1023
    const int b   = p >> 8;
    const int j   = p & 255;
    const int t    = threadIdx.x;
    const int lane = t & 63;              // h index in main loop
    const int w    = t >> 6;              // wave 0..3

    __shared__ float e_s[N_][FE_];        // 8 KB edge column j
    __shared__ float hpart[4][H_];
    __shared__ float Hsum[H_];
    __shared__ float contrib[CIN_][COUT_];

    // ---- stage edge column: thread t loads row i=t (32 B, two b128) ----
    {
        const float4* src = (const float4*)(edge_adj +
            (((size_t)b * N_ + t) * N_ + j) * FE_);
        float4 a0 = src[0];
        float4 a1 = src[1];
        float4* dst = (float4*)(&e_s[t][0]);
        dst[0] = a0;
        dst[1] = a1;
    }

    // W1 column for h=lane: coalesced (256B per f), lives in 9 VGPRs
    float w1r[FE_];
    #pragma unroll
    for (int f = 0; f < FE_; ++f) w1r[f] = W1[f * H_ + lane];
    const float b1r = b1[lane];

    __syncthreads();

    // ---- main loop: wave w owns i in [w*64, w*64+64); e_s reads are
    // wave-uniform -> LDS broadcast (conflict-free). Two independent
    // accumulator chains (even/odd i) for ILP.
    float accA = 0.f, accB = 0.f;
    const int i0 = w * 64;
    #pragma unroll 8
    for (int k = 0; k < 64; k += 2) {
        const float4* ev0 = (const float4*)(&e_s[i0 + k][0]);
        const float4* ev1 = (const float4*)(&e_s[i0 + k + 1][0]);
        const float4 ea = ev0[0], eb = ev0[1];
        const float4 fa = ev1[0], fb = ev1[1];
        float v0 = b1r, v1 = b1r;
        v0 = fmaf(ea.x, w1r[0], v0);  v1 = fmaf(fa.x, w1r[0], v1);
        v0 = fmaf(ea.y, w1r[1], v0);  v1 = fmaf(fa.y, w1r[1], v1);
        v0 = fmaf(ea.z, w1r[2], v0);  v1 = fmaf(fa.z, w1r[2], v1);
        v0 = fmaf(ea.w, w1r[3], v0);  v1 = fmaf(fa.w, w1r[3], v1);
        v0 = fmaf(eb.x, w1r[4], v0);  v1 = fmaf(fb.x, w1r[4], v1);
        v0 = fmaf(eb.y, w1r[5], v0);  v1 = fmaf(fb.y, w1r[5], v1);
        v0 = fmaf(eb.z, w1r[6], v0);  v1 = fmaf(fb.z, w1r[6], v1);
        v0 = fmaf(eb.w, w1r[7], v0);  v1 = fmaf(fb.w, w1r[7], v1);
        accA += fmaxf(v0, 0.f);
        accB += fmaxf(v1, 0.f);
    }
    hpart[w][lane] = accA + accB;
    __syncthreads();

    if (t < H_) {
        Hsum[t] = hpart[0][t] + hpart[1][t] + hpart[2][t] + hpart[3][t];
    }
    __syncthreads();

    // ---- step 2: Wsum[t], t = c*COUT+d. W2 coalesced (L2-hot 64KB).
    // 4 independent FMA chains; Hsum via b128 broadcast reads.
    float s0 = 0.f, s1 = 0.f, s2 = 0.f, s3 = 0.f;
    #pragma unroll
    for (int hq = 0; hq < 16; ++hq) {
        const float4 hv = *(const float4*)(&Hsum[hq * 4]);
        s0 = fmaf(hv.x, W2[(hq * 4 + 0) * 256 + t], s0);
        s1 = fmaf(hv.y, W2[(hq * 4 + 1) * 256 + t], s1);
        s2 = fmaf(hv.z, W2[(hq * 4 + 2) * 256 + t], s2);
        s3 = fmaf(hv.w, W2[(hq * 4 + 3) * 256 + t], s3);
    }
    const float ws = (float)N_ * b2[t] + ((s0 + s1) + (s2 + s3));

    // ---- step 3: out[d] = sum_c node[c] * (ws[c,d] + root[c,d])
    const int c = t >> 4;
    const int d = t & 15;
    const float nodec = node_attr[((size_t)b * N_ + j) * CIN_ + c];
    contrib[c][d] = nodec * (ws + root[t]);
    __syncthreads();

    if (t < COUT_) {
        float o = 0.f;
        #pragma unroll
        for (int cc = 0; cc < CIN_; ++cc) o += contrib[cc][t];
        out[((size_t)b * N_ + j) * COUT_ + t] = o;
    }
}

extern "C" void kernel_launch(void* const* d_in, const int* in_sizes, int n_in,
                              void* d_out, int out_size, void* d_ws, size_t ws_size,
                              hipStream_t stream) {
    const float* node_attr = (const float*)d_in[0];  // [B,N,CIN]
    const float* edge_adj  = (const float*)d_in[1];  // [B,N,N,FE]
    const float* W1        = (const float*)d_in[2];  // [FE,H]
    const float* b1        = (const float*)d_in[3];  // [H]
    const float* W2        = (const float*)d_in[4];  // [H,CIN*COUT]
    const float* b2        = (const float*)d_in[5];  // [CIN*COUT]
    const float* root      = (const float*)d_in[6];  // [CIN,COUT]
    float* out = (float*)d_out;                      // [B,N,COUT]

    nnconv_fused<<<dim3(B_ * N_), dim3(256), 0, stream>>>(
        node_attr, edge_adj, W1, b1, W2, b2, root, out);
}